// Round 4
// baseline (1920.335 us; speedup 1.0000x reference)
//
#include <hip/hip_runtime.h>

// ProdLayer forward: out[nids[n]] = sum_c node_mars[cids[n][c]]  (row-wise, B floats)
// Fused single dispatch; one float4 per thread per row-slice; wave = one full row.
// nt-stores keep the 128 MiB output stream from evicting node_mars (~L3-sized)
// so repeat gathers hit L3 (verified: FETCH 660->335 MB).
// Round 4: force all C gather-loads into registers BEFORE the reduce
// (VGPR_Count=12 in round 3 proved the compiler serialized them to ~2 in
// flight), and give the register allocator room via __launch_bounds__(256,4).

typedef float f32x4 __attribute__((ext_vector_type(4)));

template <int C>
__device__ __forceinline__ void prod_one(
    const float* __restrict__ node_mars,
    const int*   __restrict__ nids,
    const int*   __restrict__ cids,
    float*       __restrict__ out,
    int idx, int f4_log2, int f4_mask, int src_rows, int out_rows)
{
    const int node = idx >> f4_log2;
    const int c4   = idx & f4_mask;

    const int nid = nids[node];
    if ((unsigned)nid >= (unsigned)out_rows) return;   // safety: never write OOB

    // Stage all C loads first so they are all outstanding together (MLP=C),
    // then reduce. Bounds check is wave-uniform (node is uniform per wave).
    f32x4 v[C];
#pragma unroll
    for (int c = 0; c < C; ++c) {
        const int cid = cids[node * C + c];
        if ((unsigned)cid < (unsigned)src_rows) {      // safety: never read OOB
            v[c] = reinterpret_cast<const f32x4*>(
                node_mars + ((size_t)cid << (f4_log2 + 2)))[c4];
        } else {
            v[c] = (f32x4){0.f, 0.f, 0.f, 0.f};
        }
    }

    f32x4 acc = v[0];
#pragma unroll
    for (int c = 1; c < C; ++c) acc += v[c];

    __builtin_nontemporal_store(
        acc, reinterpret_cast<f32x4*>(out + ((size_t)nid << (f4_log2 + 2))) + c4);
}

__global__ __launch_bounds__(256, 4) void prod_fused_kernel(
    const float* __restrict__ node_mars,   // [src_rows, B]
    const int*   __restrict__ nids0,       // [n0]
    const int*   __restrict__ cids0,       // [n0, 2]
    const int*   __restrict__ nids1,       // [n1]
    const int*   __restrict__ cids1,       // [n1, 8]
    float*       __restrict__ out,         // [out_rows, B]
    int n0, int n1,
    int f4_log2,     // log2(B/4)
    int src_rows,
    int out_rows)
{
    const int f4_mask = (1 << f4_log2) - 1;
    const int total0 = n0 << f4_log2;
    const int total  = (n0 + n1) << f4_log2;
    const int stride = gridDim.x * blockDim.x;

    for (int gid = blockIdx.x * blockDim.x + threadIdx.x; gid < total; gid += stride) {
        if (gid < total0) {
            prod_one<2>(node_mars, nids0, cids0, out, gid,
                        f4_log2, f4_mask, src_rows, out_rows);
        } else {
            prod_one<8>(node_mars, nids1, cids1, out, gid - total0,
                        f4_log2, f4_mask, src_rows, out_rows);
        }
    }
}

extern "C" void kernel_launch(void* const* d_in, const int* in_sizes, int n_in,
                              void* d_out, int out_size, void* d_ws, size_t ws_size,
                              hipStream_t stream)
{
    const float* node_mars = (const float*)d_in[0];
    // d_in[1] = element_mars (zeros) — every output row is covered by nids0 ∪ nids1.
    const int* nids0 = (const int*)d_in[2];
    const int* cids0 = (const int*)d_in[3];
    const int* nids1 = (const int*)d_in[4];
    const int* cids1 = (const int*)d_in[5];

    float* out = (float*)d_out;

    const int N0 = in_sizes[2];
    const int N1 = in_sizes[4];

    // Derive B (batch) and row counts at runtime instead of hard-coding.
    const int out_rows_total = N0 + N1;
    const int B = out_size / (out_rows_total > 0 ? out_rows_total : 1);   // 256 here
    int f4_log2 = 0;
    while ((4 << f4_log2) < B) ++f4_log2;   // log2(B/4); B power of two (256 -> 6)
    const int src_rows = in_sizes[0] / (B > 0 ? B : 1);
    const int out_rows = out_size / (B > 0 ? B : 1);

    const int block = 256;
    long long total = ((long long)N0 + N1) << f4_log2;
    long long g = (total + block - 1) / block;
    if (g > 2048) g = 2048;
    if (g < 1) g = 1;

    prod_fused_kernel<<<(int)g, block, 0, stream>>>(
        node_mars, nids0, cids0, nids1, cids1, out,
        N0, N1, f4_log2, src_rows, out_rows);
}

// Round 5
// 121.391 us; speedup vs baseline: 15.8194x; 15.8194x over previous
//
#include <hip/hip_runtime.h>

// ProdLayer forward: out[nids[n]] = sum_c node_mars[cids[n][c]]  (row-wise, B floats)
// Fused single dispatch; one float4 per thread per row-slice; 64 lanes = one row.
// nt-stores keep the 128 MiB output stream from evicting node_mars (~L3-sized):
// FETCH 660->335 MB verified in round 3.
// Round 5: stage all C gather loads in NAMED registers (round 4's f32x4 v[C]
// array with conditional assignment went to scratch: WRITE_SIZE 6.9 GB, 17x
// regression). Branchless clamp keeps OOB-safety without the conditional-
// assignment pattern that defeated mem2reg.

typedef float f32x4 __attribute__((ext_vector_type(4)));

template <int C>
__device__ __forceinline__ void prod_one(
    const float* __restrict__ node_mars,
    const int*   __restrict__ nids,
    const int*   __restrict__ cids,
    float*       __restrict__ out,
    int idx, int f4_log2, int f4_mask, int src_rows, int out_rows)
{
    const int node = idx >> f4_log2;
    const int c4   = idx & f4_mask;

    const int nid = nids[node];
    if ((unsigned)nid >= (unsigned)out_rows) return;   // safety: never write OOB

    const int base = node * C;
    const int shift = f4_log2 + 2;

    // Issue all C loads back-to-back (MLP=C), then reduce with selects.
    // Clamp bad indices to row 0 (load is safe), select 0 into the sum.
    int  cid0 = 0, cid1 = 0, cid2 = 0, cid3 = 0, cid4 = 0, cid5 = 0, cid6 = 0, cid7 = 0;
    bool ok0 = false, ok1 = false, ok2 = false, ok3 = false,
         ok4 = false, ok5 = false, ok6 = false, ok7 = false;

    cid0 = cids[base + 0]; ok0 = (unsigned)cid0 < (unsigned)src_rows; cid0 = ok0 ? cid0 : 0;
    cid1 = cids[base + 1]; ok1 = (unsigned)cid1 < (unsigned)src_rows; cid1 = ok1 ? cid1 : 0;
    if constexpr (C > 2) {
        cid2 = cids[base + 2]; ok2 = (unsigned)cid2 < (unsigned)src_rows; cid2 = ok2 ? cid2 : 0;
        cid3 = cids[base + 3]; ok3 = (unsigned)cid3 < (unsigned)src_rows; cid3 = ok3 ? cid3 : 0;
        cid4 = cids[base + 4]; ok4 = (unsigned)cid4 < (unsigned)src_rows; cid4 = ok4 ? cid4 : 0;
        cid5 = cids[base + 5]; ok5 = (unsigned)cid5 < (unsigned)src_rows; cid5 = ok5 ? cid5 : 0;
        cid6 = cids[base + 6]; ok6 = (unsigned)cid6 < (unsigned)src_rows; cid6 = ok6 ? cid6 : 0;
        cid7 = cids[base + 7]; ok7 = (unsigned)cid7 < (unsigned)src_rows; cid7 = ok7 ? cid7 : 0;
    }

    const f32x4 zero = {0.f, 0.f, 0.f, 0.f};
    f32x4 v0 = zero, v1 = zero, v2 = zero, v3 = zero,
          v4 = zero, v5 = zero, v6 = zero, v7 = zero;

    v0 = reinterpret_cast<const f32x4*>(node_mars + ((size_t)cid0 << shift))[c4];
    v1 = reinterpret_cast<const f32x4*>(node_mars + ((size_t)cid1 << shift))[c4];
    if constexpr (C > 2) {
        v2 = reinterpret_cast<const f32x4*>(node_mars + ((size_t)cid2 << shift))[c4];
        v3 = reinterpret_cast<const f32x4*>(node_mars + ((size_t)cid3 << shift))[c4];
        v4 = reinterpret_cast<const f32x4*>(node_mars + ((size_t)cid4 << shift))[c4];
        v5 = reinterpret_cast<const f32x4*>(node_mars + ((size_t)cid5 << shift))[c4];
        v6 = reinterpret_cast<const f32x4*>(node_mars + ((size_t)cid6 << shift))[c4];
        v7 = reinterpret_cast<const f32x4*>(node_mars + ((size_t)cid7 << shift))[c4];
    }

    f32x4 acc = (ok0 ? v0 : zero) + (ok1 ? v1 : zero);
    if constexpr (C > 2) {
        acc += (ok2 ? v2 : zero);
        acc += (ok3 ? v3 : zero);
        acc += (ok4 ? v4 : zero);
        acc += (ok5 ? v5 : zero);
        acc += (ok6 ? v6 : zero);
        acc += (ok7 ? v7 : zero);
    }

    __builtin_nontemporal_store(
        acc, reinterpret_cast<f32x4*>(out + ((size_t)nid << shift)) + c4);
}

__global__ __launch_bounds__(256, 6) void prod_fused_kernel(
    const float* __restrict__ node_mars,   // [src_rows, B]
    const int*   __restrict__ nids0,       // [n0]
    const int*   __restrict__ cids0,       // [n0, 2]
    const int*   __restrict__ nids1,       // [n1]
    const int*   __restrict__ cids1,       // [n1, 8]
    float*       __restrict__ out,         // [out_rows, B]
    int n0, int n1,
    int f4_log2,     // log2(B/4)
    int src_rows,
    int out_rows)
{
    const int f4_mask = (1 << f4_log2) - 1;
    const int total0 = n0 << f4_log2;
    const int total  = (n0 + n1) << f4_log2;
    const int stride = gridDim.x * blockDim.x;

    for (int gid = blockIdx.x * blockDim.x + threadIdx.x; gid < total; gid += stride) {
        if (gid < total0) {
            prod_one<2>(node_mars, nids0, cids0, out, gid,
                        f4_log2, f4_mask, src_rows, out_rows);
        } else {
            prod_one<8>(node_mars, nids1, cids1, out, gid - total0,
                        f4_log2, f4_mask, src_rows, out_rows);
        }
    }
}

extern "C" void kernel_launch(void* const* d_in, const int* in_sizes, int n_in,
                              void* d_out, int out_size, void* d_ws, size_t ws_size,
                              hipStream_t stream)
{
    const float* node_mars = (const float*)d_in[0];
    // d_in[1] = element_mars (zeros) — every output row is covered by nids0 ∪ nids1.
    const int* nids0 = (const int*)d_in[2];
    const int* cids0 = (const int*)d_in[3];
    const int* nids1 = (const int*)d_in[4];
    const int* cids1 = (const int*)d_in[5];

    float* out = (float*)d_out;

    const int N0 = in_sizes[2];
    const int N1 = in_sizes[4];

    // Derive B (batch) and row counts at runtime instead of hard-coding.
    const int out_rows_total = N0 + N1;
    const int B = out_size / (out_rows_total > 0 ? out_rows_total : 1);   // 256 here
    int f4_log2 = 0;
    while ((4 << f4_log2) < B) ++f4_log2;   // log2(B/4); B power of two (256 -> 6)
    const int src_rows = in_sizes[0] / (B > 0 ? B : 1);
    const int out_rows = out_size / (B > 0 ? B : 1);

    if (src_rows <= 0 || out_rows <= 0) return;

    const int block = 256;
    long long total = ((long long)N0 + N1) << f4_log2;
    long long g = (total + block - 1) / block;
    if (g > 2048) g = 2048;
    if (g < 1) g = 1;

    prod_fused_kernel<<<(int)g, block, 0, stream>>>(
        node_mars, nids0, cids0, nids1, cids1, out,
        N0, N1, f4_log2, src_rows, out_rows);
}

// Round 6
// 120.304 us; speedup vs baseline: 15.9623x; 1.0090x over previous
//
#include <hip/hip_runtime.h>

// ProdLayer forward: out[nids[n]] = sum_c node_mars[cids[n][c]]  (row-wise, B floats)
// Fused single dispatch; one float4 per thread per row-slice; 64 lanes = one row.
// nt-stores keep the 128 MiB output stream from evicting node_mars (~L3-sized):
// FETCH 660->335 MB verified in round 3.
// Round 6: round-3 structure (simple accumulate loop: 12 VGPR / 89% occupancy
// beat round-5's 8-deep staged loads 115 vs 121 us) + SCALAR index loads:
// node = gid>>6 is wave-uniform (wave gid ranges are 64-aligned), so nids/cids
// loads are broadcast -> route them through readfirstlane/s_load to halve the
// VMEM instruction count (group 1: was 9 uniform vector loads per 8 gathers).

typedef float f32x4 __attribute__((ext_vector_type(4)));

template <int C>
__device__ __forceinline__ void prod_one(
    const float* __restrict__ node_mars,
    const int*   __restrict__ nids,
    const int*   __restrict__ cids,
    float*       __restrict__ out,
    int idx, int f4_log2, int f4_mask, int src_rows, int out_rows)
{
    // idx>>f4_log2 is identical across the 64 lanes of a wave (gid ranges are
    // 64-aligned and f4_log2 == 6 here); readfirstlane makes that provable so
    // the nids/cids loads become scalar (s_load) instead of 64-lane broadcasts.
    const int node = __builtin_amdgcn_readfirstlane(idx >> f4_log2);
    const int c4   = idx & f4_mask;

    const int nid = nids[node];
    if ((unsigned)nid >= (unsigned)out_rows) return;   // safety: never write OOB

    const int shift = f4_log2 + 2;

    f32x4 acc = {0.f, 0.f, 0.f, 0.f};
#pragma unroll
    for (int c = 0; c < C; ++c) {
        const int cid = cids[node * C + c];
        if ((unsigned)cid < (unsigned)src_rows) {      // safety: never read OOB
            const f32x4 v = reinterpret_cast<const f32x4*>(
                node_mars + ((size_t)cid << shift))[c4];
            acc += v;
        }
    }

    __builtin_nontemporal_store(
        acc, reinterpret_cast<f32x4*>(out + ((size_t)nid << shift)) + c4);
}

__global__ __launch_bounds__(256) void prod_fused_kernel(
    const float* __restrict__ node_mars,   // [src_rows, B]
    const int*   __restrict__ nids0,       // [n0]
    const int*   __restrict__ cids0,       // [n0, 2]
    const int*   __restrict__ nids1,       // [n1]
    const int*   __restrict__ cids1,       // [n1, 8]
    float*       __restrict__ out,         // [out_rows, B]
    int n0, int n1,
    int f4_log2,     // log2(B/4)
    int src_rows,
    int out_rows)
{
    const int f4_mask = (1 << f4_log2) - 1;
    const int total0 = n0 << f4_log2;
    const int total  = (n0 + n1) << f4_log2;
    const int stride = gridDim.x * blockDim.x;

    for (int gid = blockIdx.x * blockDim.x + threadIdx.x; gid < total; gid += stride) {
        if (gid < total0) {
            prod_one<2>(node_mars, nids0, cids0, out, gid,
                        f4_log2, f4_mask, src_rows, out_rows);
        } else {
            prod_one<8>(node_mars, nids1, cids1, out, gid - total0,
                        f4_log2, f4_mask, src_rows, out_rows);
        }
    }
}

extern "C" void kernel_launch(void* const* d_in, const int* in_sizes, int n_in,
                              void* d_out, int out_size, void* d_ws, size_t ws_size,
                              hipStream_t stream)
{
    const float* node_mars = (const float*)d_in[0];
    // d_in[1] = element_mars (zeros) — every output row is covered by nids0 ∪ nids1.
    const int* nids0 = (const int*)d_in[2];
    const int* cids0 = (const int*)d_in[3];
    const int* nids1 = (const int*)d_in[4];
    const int* cids1 = (const int*)d_in[5];

    float* out = (float*)d_out;

    const int N0 = in_sizes[2];
    const int N1 = in_sizes[4];

    // Derive B (batch) and row counts at runtime instead of hard-coding.
    const int out_rows_total = N0 + N1;
    const int B = out_size / (out_rows_total > 0 ? out_rows_total : 1);   // 256 here
    int f4_log2 = 0;
    while ((4 << f4_log2) < B) ++f4_log2;   // log2(B/4); B power of two (256 -> 6)
    const int src_rows = in_sizes[0] / (B > 0 ? B : 1);
    const int out_rows = out_size / (B > 0 ? B : 1);

    if (src_rows <= 0 || out_rows <= 0) return;

    const int block = 256;
    long long total = ((long long)N0 + N1) << f4_log2;
    long long g = (total + block - 1) / block;
    if (g > 2048) g = 2048;
    if (g < 1) g = 1;

    prod_fused_kernel<<<(int)g, block, 0, stream>>>(
        node_mars, nids0, cids0, nids1, cids1, out,
        N0, N1, f4_log2, src_rows, out_rows);
}

// Round 7
// 113.984 us; speedup vs baseline: 16.8475x; 1.0555x over previous
//
#include <hip/hip_runtime.h>

// ProdLayer forward: out[nids[n]] = sum_c node_mars[cids[n][c]]  (row-wise, B floats)
// Fused single dispatch (both arity groups); one float4 per thread per row-slice.
// Non-temporal stores for the output: the 128 MiB write stream must not
// write-allocate into L2/L3, so node_mars (256 MiB ~= L3) stays resident and
// the mean-multiplicity-2.4 gather hits L3 instead of HBM (FETCH 660->330 MB).
//
// This is the round-3 structure, reverted to after three counter-guided
// experiments all regressed:
//  - r4: staged f32x4 v[C] array -> scratch (WRITE_SIZE 6.9 GB, 17x slower)
//  - r5: named-register 8-deep staging + launch_bounds(256,6) -> 121 us
//        (cndmask overhead + occupancy drop; latency was NOT the limiter)
//  - r6: readfirstlane/s_load indices -> 120 us (added lgkmcnt dep chain)
// The plain loop (VGPR=12, ~88% occupancy, 28+ waves/CU) is the optimum:
// demand 774 MB / 115 us = 6.8 TB/s combined memory-system rate, within ~5%
// of the 7.0-7.2 TB/s pure-write fill ceiling measured on the same chip.

typedef float f32x4 __attribute__((ext_vector_type(4)));

template <int C>
__device__ __forceinline__ void prod_one(
    const float* __restrict__ node_mars,
    const int*   __restrict__ nids,
    const int*   __restrict__ cids,
    float*       __restrict__ out,
    int idx, int f4_log2, int f4_mask, int src_rows, int out_rows)
{
    const int node = idx >> f4_log2;
    const int c4   = idx & f4_mask;

    const int nid = nids[node];
    if ((unsigned)nid >= (unsigned)out_rows) return;   // safety: never write OOB

    f32x4 acc = {0.f, 0.f, 0.f, 0.f};
#pragma unroll
    for (int c = 0; c < C; ++c) {
        const int cid = cids[node * C + c];
        if ((unsigned)cid < (unsigned)src_rows) {      // safety: never read OOB
            const f32x4 v = reinterpret_cast<const f32x4*>(
                node_mars + ((size_t)cid << (f4_log2 + 2)))[c4];
            acc += v;
        }
    }

    __builtin_nontemporal_store(
        acc, reinterpret_cast<f32x4*>(out + ((size_t)nid << (f4_log2 + 2))) + c4);
}

__global__ __launch_bounds__(256) void prod_fused_kernel(
    const float* __restrict__ node_mars,   // [src_rows, B]
    const int*   __restrict__ nids0,       // [n0]
    const int*   __restrict__ cids0,       // [n0, 2]
    const int*   __restrict__ nids1,       // [n1]
    const int*   __restrict__ cids1,       // [n1, 8]
    float*       __restrict__ out,         // [out_rows, B]
    int n0, int n1,
    int f4_log2,     // log2(B/4)
    int src_rows,
    int out_rows)
{
    const int f4_mask = (1 << f4_log2) - 1;
    const int total0 = n0 << f4_log2;
    const int total  = (n0 + n1) << f4_log2;
    const int stride = gridDim.x * blockDim.x;

    for (int gid = blockIdx.x * blockDim.x + threadIdx.x; gid < total; gid += stride) {
        if (gid < total0) {
            prod_one<2>(node_mars, nids0, cids0, out, gid,
                        f4_log2, f4_mask, src_rows, out_rows);
        } else {
            prod_one<8>(node_mars, nids1, cids1, out, gid - total0,
                        f4_log2, f4_mask, src_rows, out_rows);
        }
    }
}

extern "C" void kernel_launch(void* const* d_in, const int* in_sizes, int n_in,
                              void* d_out, int out_size, void* d_ws, size_t ws_size,
                              hipStream_t stream)
{
    const float* node_mars = (const float*)d_in[0];
    // d_in[1] = element_mars (zeros) — every output row is covered by nids0 ∪ nids1.
    const int* nids0 = (const int*)d_in[2];
    const int* cids0 = (const int*)d_in[3];
    const int* nids1 = (const int*)d_in[4];
    const int* cids1 = (const int*)d_in[5];

    float* out = (float*)d_out;

    const int N0 = in_sizes[2];
    const int N1 = in_sizes[4];

    // Derive B (batch) and row counts at runtime instead of hard-coding.
    const int out_rows_total = N0 + N1;
    const int B = out_size / (out_rows_total > 0 ? out_rows_total : 1);   // 256 here
    int f4_log2 = 0;
    while ((4 << f4_log2) < B) ++f4_log2;   // log2(B/4); B power of two (256 -> 6)
    const int src_rows = in_sizes[0] / (B > 0 ? B : 1);
    const int out_rows = out_size / (B > 0 ? B : 1);

    if (src_rows <= 0 || out_rows <= 0) return;

    const int block = 256;
    long long total = ((long long)N0 + N1) << f4_log2;
    long long g = (total + block - 1) / block;
    if (g > 2048) g = 2048;
    if (g < 1) g = 1;

    prod_fused_kernel<<<(int)g, block, 0, stream>>>(
        node_mars, nids0, cids0, nids1, cids1, out,
        N0, N1, f4_log2, src_rows, out_rows);
}